// Round 5
// baseline (7428.809 us; speedup 1.0000x reference)
//
#include <hip/hip_runtime.h>

// RecurrentGaussianActor: fused LSTM(64->256) + Linear+ReLU(256) + 2 heads(16).
// Round-6: TWO batch rows per WG (128 WGs x 512 threads), persistent T=1000.
//
// Why: rounds 0 and 4 both land at ~4.5ms with VALUBusy ~37% -- the wall is
// fixed per-step overhead (barrier + LDS latency + serial dot chain) that is
// independent of per-step work, paid once per row-step. Weight residency
// (192 regs + 131KB LDS) forces 1 WG/CU and per-step barriers, so the only
// amortization lever is more rows per weight copy: each weight h8 is read
// once and dotted against BOTH rows' h vectors (8 independent acc chains).
// CHUNK=4 (LDS: 131K whh + 16K xg + doubled row buffers = 158.8KB).
// Everything else is the proven round-0/4 pattern verbatim (volatile wreg,
// 16-col whh_l, DPP xor-1 butterfly, padded dbuf hbuf, 1 barrier/step).
// Spill tell: FETCH >= 1 GB means the allocator lost ~15 extra live regs.

#define NB 256           // total batch rows
#define GRID 128         // WGs; 2 rows per WG
#define NT 1000
#define NF 64
#define NH 256
#define NG 1024
#define NA 16
#define NTHREADS 512
#define CHUNK 4
#define NCHUNK (NT / CHUNK)
#define HHALF 68  // h2 units per padded h-half: 128 f16 = 64 h2, +4 h2 pad = 272 B

typedef _Float16 h2 __attribute__((ext_vector_type(2)));
typedef _Float16 h4 __attribute__((ext_vector_type(4)));
typedef _Float16 h8 __attribute__((ext_vector_type(8)));
typedef float f4 __attribute__((ext_vector_type(4)));

__device__ __forceinline__ float fdot2(h2 a, h2 b, float c) {
  return __builtin_amdgcn_fdot2(a, b, c, false);
}
__device__ __forceinline__ float fexp2(float x) { return __builtin_amdgcn_exp2f(x); }
__device__ __forceinline__ float frcp(float x) { return __builtin_amdgcn_rcpf(x); }
__device__ __forceinline__ float sigmoidf_(float x) {
  return frcp(1.f + fexp2(-1.4426950408889634f * x));
}
__device__ __forceinline__ float tanhfast(float x) {
  float a = fabsf(x);
  float e = fexp2(-2.8853900817779268f * a);
  float r = (1.f - e) * frcp(1.f + e);
  return __builtin_copysignf(r, x);
}
// dot of 8 f16 elements held in two h8 vectors (4 chained v_dot2_f32_f16)
__device__ __forceinline__ float dot8(h8 x, h8 w, float acc) {
  acc = fdot2(__builtin_shufflevector(x, x, 0, 1), __builtin_shufflevector(w, w, 0, 1), acc);
  acc = fdot2(__builtin_shufflevector(x, x, 2, 3), __builtin_shufflevector(w, w, 2, 3), acc);
  acc = fdot2(__builtin_shufflevector(x, x, 4, 5), __builtin_shufflevector(w, w, 4, 5), acc);
  acc = fdot2(__builtin_shufflevector(x, x, 6, 7), __builtin_shufflevector(w, w, 6, 7), acc);
  return acc;
}
// quad_perm DPP: CTRL=0xB1 -> lanes (1,0,3,2) [xor1 within each quad]
template <int CTRL>
__device__ __forceinline__ float qperm(float x) {
  return __int_as_float(
      __builtin_amdgcn_update_dpp(0, __float_as_int(x), CTRL, 0xF, 0xF, true));
}

// ---- prep: convert/pack weights to f16 pairs in workspace (round-0 verbatim) ----
__global__ void prep_kernel(const float* __restrict__ Wih, const float* __restrict__ Whh,
                            const float* __restrict__ bih, const float* __restrict__ bhh,
                            const float* __restrict__ W2, const float* __restrict__ Wm,
                            const float* __restrict__ Ws,
                            h2* __restrict__ whh, h2* __restrict__ wih,
                            h2* __restrict__ w2w, h2* __restrict__ wmh,
                            float* __restrict__ bg) {
  int i = blockIdx.x * 256 + threadIdx.x;
  if (i < 1024 * 128) {  // W_hh [1024][256] -> [1024][128] pairs
    int j = i >> 7, p = i & 127;
    whh[i] = h2{(_Float16)Whh[j * 256 + 2 * p], (_Float16)Whh[j * 256 + 2 * p + 1]};
  }
  if (i < 1024 * 32) {   // W_ih [1024][64] -> [1024][32] pairs
    int j = i >> 5, p = i & 31;
    wih[i] = h2{(_Float16)Wih[j * 64 + 2 * p], (_Float16)Wih[j * 64 + 2 * p + 1]};
  }
  if (i < 256 * 128) {   // W2 [256][256] -> [256][128] pairs
    int j = i >> 7, p = i & 127;
    w2w[i] = h2{(_Float16)W2[j * 256 + 2 * p], (_Float16)W2[j * 256 + 2 * p + 1]};
  }
  if (i < 32 * 128) {    // Wm rows 0..15, Ws rows 16..31
    int j = i >> 7, p = i & 127;
    float v0, v1;
    if (j < 16) { v0 = Wm[j * 256 + 2 * p]; v1 = Wm[j * 256 + 2 * p + 1]; }
    else        { v0 = Ws[(j - 16) * 256 + 2 * p]; v1 = Ws[(j - 16) * 256 + 2 * p + 1]; }
    wmh[i] = h2{(_Float16)v0, (_Float16)v1};
  }
  if (i < 1024) bg[i] = bih[i] + bhh[i];
}

// ---- main fused persistent kernel: 1 WG per TWO batch rows ----
__global__ __launch_bounds__(NTHREADS, 2) void actor_kernel(
    const float* __restrict__ obs,
    const h2* __restrict__ whh, const h2* __restrict__ wih,
    const h2* __restrict__ w2w, const h2* __restrict__ wmh,
    const float* __restrict__ bg, const float* __restrict__ b2,
    const float* __restrict__ bm, const float* __restrict__ bs,
    float* __restrict__ out) {
  __shared__ __align__(16) h8 whh_l[16 * NTHREADS];        // 131072 B
  __shared__ __align__(16) _Float16 xg_l[CHUNK * 2 * NG];  // 16384 B [t][rb][u][4g]
  __shared__ __align__(16) h2 hbuf[2][2][2 * HHALF];       // 2176 B  dbuf x 2 rows
  __shared__ __align__(16) h2 hch[2][CHUNK][NH / 2];       // 4096 B  h history
  __shared__ __align__(16) h2 xbuf[2][CHUNK][NF / 2];      // 1024 B  obs chunk
  __shared__ __align__(16) h2 x2b[2][CHUNK][NH / 2];       // 4096 B  layer2 out
  // total 158848 B <= 163840

  const int tid = threadIdx.x;
  const int b = blockIdx.x;       // handles batch rows 2b, 2b+1
  const int q = tid >> 1;         // hidden unit owned by this lane pair
  const int jhalf = tid & 1;      // h-half [128*jhalf, 128*jhalf+128)

  // ---- register-resident W_hh: h8s 4..15 of own half, 4 gate rows of q ----
  // 48 x h8 = 192 regs (proven footprint). VOLATILE: no remat in step loop.
  h8 wreg[48];
  {
    const volatile h8* vw = (const volatile h8*)whh;  // row stride = 32 h8
#pragma unroll
    for (int g = 0; g < 4; g++)
#pragma unroll
      for (int jj = 0; jj < 12; jj++)
        wreg[g * 12 + jj] = vw[(g * 256 + q) * 32 + jhalf * 16 + 4 + jj];
  }
  // ---- LDS-resident W_hh: h8s 0..3 of own half, column (g*4+s), idx tid ----
  {
    const h8* whh8 = (const h8*)whh;
#pragma unroll
    for (int g = 0; g < 4; g++)
#pragma unroll
      for (int s = 0; s < 4; s++)
        whh_l[(g * 4 + s) * NTHREADS + tid] = whh8[(g * 256 + q) * 32 + jhalf * 16 + s];
  }
  if (tid < 2 * 2 * HHALF) ((h2*)hbuf)[tid] = h2{(_Float16)0.f, (_Float16)0.f};
  float c0 = 0.f, c1 = 0.f;  // cell states of unit q, rows 0/1 (pair-replicated)
  const float bg0 = bg[tid], bg1 = bg[tid + 512];
  const float b2v = b2[tid & 255];
  const int oh = tid & 31;
  const float headb = (oh < NA) ? bm[oh] : bs[oh - NA];
  __syncthreads();

  float* out_means = out;
  float* out_stds = out + (size_t)NB * NT * NA;

  for (int ch = 0; ch < NCHUNK; ++ch) {
    const int t0 = ch * CHUNK;

    // ---- stage obs chunk (2 rows x 4 t) -> f16 pairs in LDS ----
    if (tid < 128) {
      int rb = tid >> 6, tq = (tid >> 4) & 3, fq = tid & 15;
      const float* ob = obs + ((size_t)(2 * b + rb) * NT + (t0 + tq)) * NF;
      f4 v = *(const f4*)(ob + fq * 4);
      xbuf[rb][tq][fq * 2] = h2{(_Float16)v[0], (_Float16)v[1]};
      xbuf[rb][tq][fq * 2 + 1] = h2{(_Float16)v[2], (_Float16)v[3]};
    }
    __syncthreads();

    // ---- xg for gate rows tid, tid+512 x 2 batch rows x 4 t ----
#pragma unroll
    for (int rr = 0; rr < 2; ++rr) {
      const int row = tid + rr * 512;
      const float bias = rr ? bg1 : bg0;
      float acc[2][4];
#pragma unroll
      for (int rb = 0; rb < 2; rb++)
#pragma unroll
        for (int tq = 0; tq < 4; tq++) acc[rb][tq] = bias;
      const h8* wrow = (const h8*)wih + row * 8;
#pragma unroll
      for (int jh = 0; jh < 2; jh++) {
        h8 w[4];
#pragma unroll
        for (int qq = 0; qq < 4; qq++) w[qq] = wrow[jh * 4 + qq];
#pragma unroll
        for (int rb = 0; rb < 2; rb++)
#pragma unroll
          for (int tq = 0; tq < 4; tq++)
#pragma unroll
            for (int qq = 0; qq < 4; qq++) {
              h8 xv = *(const h8*)&xbuf[rb][tq][jh * 16 + qq * 4];
              acc[rb][tq] = dot8(xv, w[qq], acc[rb][tq]);
            }
      }
      const int g = row >> 8, uu = row & 255;
#pragma unroll
      for (int rb = 0; rb < 2; rb++)
#pragma unroll
        for (int tq = 0; tq < 4; tq++)
          xg_l[((tq * 2 + rb) * 256 + uu) * 4 + g] = (_Float16)acc[rb][tq];
    }
    __syncthreads();

    // ---- 4 recurrent LSTM steps x 2 rows, ONE barrier each ----
    for (int t = 0; t < CHUNK; t++) {
      const _Float16* hbA = (const _Float16*)&hbuf[t & 1][0][jhalf * HHALF];
      const _Float16* hbB = (const _Float16*)&hbuf[t & 1][1][jhalf * HHALF];
      h4 xgA = *(const h4*)&xg_l[((t * 2 + 0) * 256 + q) * 4];
      h4 xgB = *(const h4*)&xg_l[((t * 2 + 1) * 256 + q) * 4];
      float pa0 = 0.f, pa1 = 0.f, pa2 = 0.f, pa3 = 0.f;
      float pb0 = 0.f, pb1 = 0.f, pb2 = 0.f, pb3 = 0.f;
      // LDS-weight part: each w h8 read ONCE, dotted against both rows' hv.
#pragma unroll
      for (int s = 0; s < 4; s++) {
        h8 w0 = whh_l[(0 * 4 + s) * NTHREADS + tid];
        h8 w1 = whh_l[(1 * 4 + s) * NTHREADS + tid];
        h8 w2_ = whh_l[(2 * 4 + s) * NTHREADS + tid];
        h8 w3_ = whh_l[(3 * 4 + s) * NTHREADS + tid];
        h8 hvA = *(const h8*)(hbA + s * 8);
        pa0 = dot8(hvA, w0, pa0);
        pa1 = dot8(hvA, w1, pa1);
        pa2 = dot8(hvA, w2_, pa2);
        pa3 = dot8(hvA, w3_, pa3);
        h8 hvB = *(const h8*)(hbB + s * 8);
        pb0 = dot8(hvB, w0, pb0);
        pb1 = dot8(hvB, w1, pb1);
        pb2 = dot8(hvB, w2_, pb2);
        pb3 = dot8(hvB, w3_, pb3);
      }
      // register-weight part: wreg reused for both rows.
#pragma unroll
      for (int jj = 0; jj < 12; jj++) {
        h8 hvA = *(const h8*)(hbA + 32 + jj * 8);
        pa0 = dot8(hvA, wreg[jj], pa0);
        pa1 = dot8(hvA, wreg[12 + jj], pa1);
        pa2 = dot8(hvA, wreg[24 + jj], pa2);
        pa3 = dot8(hvA, wreg[36 + jj], pa3);
        h8 hvB = *(const h8*)(hbB + 32 + jj * 8);
        pb0 = dot8(hvB, wreg[jj], pb0);
        pb1 = dot8(hvB, wreg[12 + jj], pb1);
        pb2 = dot8(hvB, wreg[24 + jj], pb2);
        pb3 = dot8(hvB, wreg[36 + jj], pb3);
      }
      // xor-1 DPP butterfly: both lanes of the pair get all 8 full sums.
      pa0 += qperm<0xB1>(pa0);
      pa1 += qperm<0xB1>(pa1);
      pa2 += qperm<0xB1>(pa2);
      pa3 += qperm<0xB1>(pa3);
      pb0 += qperm<0xB1>(pb0);
      pb1 += qperm<0xB1>(pb1);
      pb2 += qperm<0xB1>(pb2);
      pb3 += qperm<0xB1>(pb3);
      float gi = sigmoidf_(pa0 + (float)xgA[0]);
      float gf = sigmoidf_(pa1 + (float)xgA[1]);
      float gg = tanhfast(pa2 + (float)xgA[2]);
      float go = sigmoidf_(pa3 + (float)xgA[3]);
      c0 = gf * c0 + gi * gg;
      float h0 = go * tanhfast(c0);
      gi = sigmoidf_(pb0 + (float)xgB[0]);
      gf = sigmoidf_(pb1 + (float)xgB[1]);
      gg = tanhfast(pb2 + (float)xgB[2]);
      go = sigmoidf_(pb3 + (float)xgB[3]);
      c1 = gf * c1 + gi * gg;
      float h1 = go * tanhfast(c1);
      if (jhalf == 0) {  // one lane per unit publishes both rows
        _Float16 ha = (_Float16)h0, hb_ = (_Float16)h1;
        ((_Float16*)&hbuf[(t + 1) & 1][0][(q >> 7) * HHALF])[q & 127] = ha;
        ((_Float16*)&hbuf[(t + 1) & 1][1][(q >> 7) * HHALF])[q & 127] = hb_;
        ((_Float16*)&hch[0][t][0])[q] = ha;
        ((_Float16*)&hch[1][t][0])[q] = hb_;
      }
      __syncthreads();  // h(t+1) visible; hbuf[t&1] free for step t+2's write
    }

    // ---- layer2: x2 = relu(h @ W2^T + b2); thread = (o, batch row) ----
    {
      const int o = tid & 255;
      const int rb = tid >> 8;
      float acc[4] = {b2v, b2v, b2v, b2v};
      const h8* wrow = (const h8*)w2w + o * 32;
#pragma unroll 2
      for (int c = 0; c < 32; c++) {
        h8 w = wrow[c];
#pragma unroll
        for (int tq = 0; tq < 4; tq++) {
          h8 xv = *(const h8*)&hch[rb][tq][c * 4];
          acc[tq] = dot8(xv, w, acc[tq]);
        }
      }
#pragma unroll
      for (int tq = 0; tq < 4; tq++)
        ((_Float16*)&x2b[rb][tq][0])[o] = (_Float16)fmaxf(acc[tq], 0.f);
    }
    __syncthreads();

    // ---- heads: 32 outputs x (2 rows x 4 t) on first 256 threads ----
    if (tid < 256) {
      const int rb = tid >> 7;
      const int tt = (tid >> 5) & 3;
      const h8* wrow = (const h8*)wmh + oh * 32;
      float acc = 0.f;
#pragma unroll 4
      for (int c = 0; c < 32; c++) {
        h8 xv = *(const h8*)&x2b[rb][tt][c * 4];
        acc = dot8(xv, wrow[c], acc);
      }
      acc += headb;
      const size_t idx = ((size_t)(2 * b + rb) * NT + (t0 + tt)) * NA + (oh & 15);
      if (oh < NA) {
        out_means[idx] = acc;
      } else {
        float ls = fminf(fmaxf(acc, -20.f), 2.f);
        out_stds[idx] = fexp2(1.4426950408889634f * ls);
      }
    }
    // no trailing barrier: next chunk's first write to x2b (its layer2) is
    // separated from these reads by the staging/xg/step barriers.
  }
}

extern "C" void kernel_launch(void* const* d_in, const int* in_sizes, int n_in,
                              void* d_out, int out_size, void* d_ws, size_t ws_size,
                              hipStream_t stream) {
  const float* obs = (const float*)d_in[0];
  const float* Wih = (const float*)d_in[1];
  const float* Whh = (const float*)d_in[2];
  const float* bih = (const float*)d_in[3];
  const float* bhh = (const float*)d_in[4];
  const float* W2 = (const float*)d_in[5];
  const float* b2 = (const float*)d_in[6];
  const float* Wm = (const float*)d_in[7];
  const float* bm = (const float*)d_in[8];
  const float* Ws = (const float*)d_in[9];
  const float* bs = (const float*)d_in[10];

  char* ws = (char*)d_ws;
  h2* whh = (h2*)(ws + 0);            // 512 KB
  h2* wih = (h2*)(ws + 524288);       // 128 KB
  h2* w2w = (h2*)(ws + 655360);       // 128 KB
  h2* wmh = (h2*)(ws + 786432);       // 16 KB
  float* bg = (float*)(ws + 802816);  // 4 KB

  prep_kernel<<<512, 256, 0, stream>>>(Wih, Whh, bih, bhh, W2, Wm, Ws,
                                       whh, wih, w2w, wmh, bg);
  actor_kernel<<<GRID, NTHREADS, 0, stream>>>(obs, whh, wih, w2w, wmh, bg, b2,
                                              bm, bs, (float*)d_out);
}